// Round 3
// baseline (223.713 us; speedup 1.0000x reference)
//
#include <hip/hip_runtime.h>
#include <math.h>

constexpr int B = 8, A = 100000, C = 80, M = 32;
constexpr int C4 = C / 4;                       // 20 float4 per anchor row
constexpr int TPB = 128;                        // threads per block (2 waves)
constexpr int STREAM_BPI = 625;                 // stream blocks per image
constexpr int F4PT = 25;                        // float4 per thread = 5 batches x 5 loads
constexpr int STREAM_BLOCKS = STREAM_BPI * B;   // 5000 (625*128*25 = 2e6 = A*C/4 exactly)
constexpr int ASSIGN_BPI = (A + TPB - 1) / TPB; // 782
constexpr int ASSIGN_BLOCKS = ASSIGN_BPI * B;   // 6256
constexpr float NEG_SCALE = 0.75f * 0.6931471805599453f; // 0.75*ln2

__global__ __launch_bounds__(128) void focal_fused(
    const float* __restrict__ cls,       // [B,A,C]
    const float* __restrict__ regs,      // [B,A,4]
    const float* __restrict__ anchors,   // [1,A,4]
    const float* __restrict__ ann,       // [B,M,5]
    float* __restrict__ raw_acc,
    float* __restrict__ corr_acc,
    float* __restrict__ reg_acc,
    unsigned int* __restrict__ npos_acc)
{
    __shared__ float bx1[M], by1[M], bx2[M], by2[M], blab[M], barea[M];
    __shared__ float sred0[2], sred1[2];
    __shared__ int   sredp[2];

    const int bid = blockIdx.x;
    const int tid = threadIdx.x;

    if (bid < STREAM_BLOCKS) {
        // ---------------- STREAM: sum p^2 * log2(1-p) over a contiguous chunk
        const int b    = bid / STREAM_BPI;
        const int cblk = bid - b * STREAM_BPI;
        const float* base = cls + (size_t)b * ((size_t)A * C)
                                + (size_t)cblk * (TPB * F4PT * 4);
        float acc0 = 0.f, acc1 = 0.f;
        #pragma unroll
        for (int j = 0; j < 5; ++j) {
            const float* p0 = base + ((size_t)j * 5 * TPB + tid) * 4;
            float4 v0 = *(const float4*)(p0);
            float4 v1 = *(const float4*)(p0 + TPB * 4);
            float4 v2 = *(const float4*)(p0 + 2 * TPB * 4);
            float4 v3 = *(const float4*)(p0 + 3 * TPB * 4);
            float4 v4 = *(const float4*)(p0 + 4 * TPB * 4);
            acc0 = fmaf(v0.x * v0.x, __log2f(1.f - v0.x), acc0);
            acc1 = fmaf(v0.y * v0.y, __log2f(1.f - v0.y), acc1);
            acc0 = fmaf(v0.z * v0.z, __log2f(1.f - v0.z), acc0);
            acc1 = fmaf(v0.w * v0.w, __log2f(1.f - v0.w), acc1);
            acc0 = fmaf(v1.x * v1.x, __log2f(1.f - v1.x), acc0);
            acc1 = fmaf(v1.y * v1.y, __log2f(1.f - v1.y), acc1);
            acc0 = fmaf(v1.z * v1.z, __log2f(1.f - v1.z), acc0);
            acc1 = fmaf(v1.w * v1.w, __log2f(1.f - v1.w), acc1);
            acc0 = fmaf(v2.x * v2.x, __log2f(1.f - v2.x), acc0);
            acc1 = fmaf(v2.y * v2.y, __log2f(1.f - v2.y), acc1);
            acc0 = fmaf(v2.z * v2.z, __log2f(1.f - v2.z), acc0);
            acc1 = fmaf(v2.w * v2.w, __log2f(1.f - v2.w), acc1);
            acc0 = fmaf(v3.x * v3.x, __log2f(1.f - v3.x), acc0);
            acc1 = fmaf(v3.y * v3.y, __log2f(1.f - v3.y), acc1);
            acc0 = fmaf(v3.z * v3.z, __log2f(1.f - v3.z), acc0);
            acc1 = fmaf(v3.w * v3.w, __log2f(1.f - v3.w), acc1);
            acc0 = fmaf(v4.x * v4.x, __log2f(1.f - v4.x), acc0);
            acc1 = fmaf(v4.y * v4.y, __log2f(1.f - v4.y), acc1);
            acc0 = fmaf(v4.z * v4.z, __log2f(1.f - v4.z), acc0);
            acc1 = fmaf(v4.w * v4.w, __log2f(1.f - v4.w), acc1);
        }
        float acc = acc0 + acc1;
        #pragma unroll
        for (int off = 32; off; off >>= 1) acc += __shfl_down(acc, off);
        if ((tid & 63) == 0) sred0[tid >> 6] = acc;
        __syncthreads();
        if (tid == 0) atomicAdd(&raw_acc[b], sred0[0] + sred0[1]);
    } else {
        // ---------------- ASSIGN: IoU, corrections, reg loss, npos
        const int idx  = bid - STREAM_BLOCKS;
        const int b    = idx / ASSIGN_BPI;
        const int ablk = idx - b * ASSIGN_BPI;
        const int a    = ablk * TPB + tid;

        if (tid < M) {
            const float* p = ann + ((size_t)b * M + tid) * 5;
            float x1 = p[0], y1 = p[1], x2 = p[2], y2 = p[3];
            bx1[tid] = x1; by1[tid] = y1; bx2[tid] = x2; by2[tid] = y2;
            blab[tid] = p[4];
            barea[tid] = (x2 - x1) * (y2 - y1);
        }
        __syncthreads();

        float my_corr = 0.f, my_reg = 0.f;
        int   my_pos  = 0;
        if (a < A) {
            float4 ab = *(const float4*)(anchors + (size_t)a * 4);
            const float ax1 = ab.x, ay1 = ab.y, ax2 = ab.z, ay2 = ab.w;
            const float area_a = (ax2 - ax1) * (ay2 - ay1);
            float best = -2.f; int barg = 0;
            #pragma unroll
            for (int m = 0; m < M; ++m) {
                float iw = fminf(ax2, bx2[m]) - fmaxf(ax1, bx1[m]);
                float ih = fminf(ay2, by2[m]) - fmaxf(ay1, by1[m]);
                iw = fmaxf(iw, 0.f); ih = fmaxf(ih, 0.f);
                float inter = iw * ih;
                float ua  = fmaxf(area_a + barea[m] - inter, 1e-8f);
                float iou = inter / ua;
                if (blab[m] == -1.0f) iou = -1.0f;
                if (iou > best) { best = iou; barg = m; }
            }
            const bool pos = best >= 0.4f;
            const bool neg = best < 0.3f;
            const float* row = cls + ((size_t)b * A + a) * C;
            if (pos) {
                my_pos = 1;
                const int cd = (int)blab[barg];
                float p = row[cd];
                p = fminf(fmaxf(p, 1e-4f), 0.9999f);
                const float omp = 1.f - p;
                my_corr = 0.25f * omp * omp * (-__logf(p))
                        - 0.75f * p * p * (-__logf(omp));
                const float aw = ax2 - ax1, ah = ay2 - ay1;
                const float acx = ax1 + 0.5f * aw, acy = ay1 + 0.5f * ah;
                float gw = bx2[barg] - bx1[barg], gh = by2[barg] - by1[barg];
                const float gcx = bx1[barg] + 0.5f * gw, gcy = by1[barg] + 0.5f * gh;
                gw = fmaxf(gw, 1.f); gh = fmaxf(gh, 1.f);
                const float t0 = ((gcx - acx) / aw) / 0.1f;
                const float t1 = ((gcy - acy) / ah) / 0.1f;
                const float t2 = __logf(gw / aw) / 0.2f;
                const float t3 = __logf(gh / ah) / 0.2f;
                float4 rp4 = *(const float4*)(regs + ((size_t)b * A + a) * 4);
                const float d0 = fabsf(t0 - rp4.x), d1 = fabsf(t1 - rp4.y);
                const float d2 = fabsf(t2 - rp4.z), d3 = fabsf(t3 - rp4.w);
                my_reg = (d0 <= 1.f ? 0.5f * d0 * d0 : d0 - 0.5f)
                       + (d1 <= 1.f ? 0.5f * d1 * d1 : d1 - 0.5f)
                       + (d2 <= 1.f ? 0.5f * d2 * d2 : d2 - 0.5f)
                       + (d3 <= 1.f ? 0.5f * d3 * d3 : d3 - 0.5f);
            } else if (!neg) {
                float c2 = 0.f;
                #pragma unroll 5
                for (int c4i = 0; c4i < C4; ++c4i) {
                    float4 v = *(const float4*)(row + c4i * 4);
                    c2 += v.x * v.x * __log2f(1.f - v.x)
                        + v.y * v.y * __log2f(1.f - v.y)
                        + v.z * v.z * __log2f(1.f - v.z)
                        + v.w * v.w * __log2f(1.f - v.w);
                }
                my_corr = NEG_SCALE * c2;   // c2<0: cancels the streamed row
            }
        }
        #pragma unroll
        for (int off = 32; off; off >>= 1) {
            my_corr += __shfl_down(my_corr, off);
            my_reg  += __shfl_down(my_reg, off);
            my_pos  += __shfl_down(my_pos, off);
        }
        if ((tid & 63) == 0) {
            sred0[tid >> 6] = my_corr;
            sred1[tid >> 6] = my_reg;
            sredp[tid >> 6] = my_pos;
        }
        __syncthreads();
        if (tid == 0) {
            atomicAdd(&corr_acc[b], sred0[0] + sred0[1]);
            atomicAdd(&reg_acc[b],  sred1[0] + sred1[1]);
            atomicAdd(&npos_acc[b], (unsigned)(sredp[0] + sredp[1]));
        }
    }
}

__global__ void focal_finalize(const float* __restrict__ raw_acc,
                               const float* __restrict__ corr_acc,
                               const float* __restrict__ reg_acc,
                               const unsigned int* __restrict__ npos_acc,
                               float* __restrict__ out)
{
    if (threadIdx.x == 0) {
        float cm = 0.f, rm = 0.f; unsigned tot = 0u;
        #pragma unroll
        for (int b = 0; b < B; ++b) {
            const unsigned np = npos_acc[b];
            const float npf = (float)np;
            const float cls_sum = -NEG_SCALE * raw_acc[b] + corr_acc[b];
            cm += cls_sum / fmaxf(npf, 1.f);
            rm += (np > 0u) ? reg_acc[b] / fmaxf(npf * 4.f, 1.f) : 0.f;
            tot += np;
        }
        out[0] = cm / (float)B;
        out[1] = rm / (float)B;
        out[2] = (float)tot;
    }
}

extern "C" void kernel_launch(void* const* d_in, const int* in_sizes, int n_in,
                              void* d_out, int out_size, void* d_ws, size_t ws_size,
                              hipStream_t stream) {
    const float* cls     = (const float*)d_in[0];
    const float* regs    = (const float*)d_in[1];
    const float* anchors = (const float*)d_in[2];
    const float* ann     = (const float*)d_in[3];
    float* out = (float*)d_out;

    float* raw_acc  = (float*)d_ws;
    float* corr_acc = raw_acc + B;
    float* reg_acc  = corr_acc + B;
    unsigned int* npos_acc = (unsigned int*)(reg_acc + B);

    hipMemsetAsync(d_ws, 0, 4 * B * sizeof(float), stream);

    focal_fused<<<STREAM_BLOCKS + ASSIGN_BLOCKS, TPB, 0, stream>>>(
        cls, regs, anchors, ann, raw_acc, corr_acc, reg_acc, npos_acc);
    focal_finalize<<<1, 64, 0, stream>>>(raw_acc, corr_acc, reg_acc, npos_acc, out);
}

// Round 4
// 147.886 us; speedup vs baseline: 1.5127x; 1.5127x over previous
//
#include <hip/hip_runtime.h>
#include <math.h>

constexpr int B = 8, A = 100000, C = 80, M = 32;
constexpr int APB = 256;                        // anchors per block
constexpr int NBLK = (A + APB - 1) / APB;       // 391 (last block: 160 anchors)
constexpr int C4 = C / 4;                       // 20 float4 per anchor row
constexpr float NEG_SCALE = 0.75f * 0.6931471805599453f; // 0.75*ln2

// d_ws layout: cls_acc[B], reg_acc[B], npos_acc[B]
__global__ __launch_bounds__(256, 8) void focal_main(
    const float* __restrict__ cls,       // [B,A,C]
    const float* __restrict__ regs,      // [B,A,4]
    const float* __restrict__ anchors,   // [1,A,4]
    const float* __restrict__ ann,       // [B,M,5]
    float* __restrict__ cls_acc,
    float* __restrict__ reg_acc,
    unsigned int* __restrict__ npos_acc)
{
    const int b   = blockIdx.y;
    const int a0  = blockIdx.x * APB;
    const int tid = threadIdx.x;
    const int nA  = min(APB, A - a0);

    __shared__ float bx1[M], by1[M], bx2[M], by2[M], blab[M], barea[M];
    __shared__ float rc[4], rr[4];
    __shared__ int   rp[4];

    if (tid < M) {
        const float* p = ann + ((size_t)b * M + tid) * 5;
        float x1 = p[0], y1 = p[1], x2 = p[2], y2 = p[3];
        bx1[tid] = x1; by1[tid] = y1; bx2[tid] = x2; by2[tid] = y2;
        blab[tid] = p[4];
        barea[tid] = (x2 - x1) * (y2 - y1);
    }
    __syncthreads();

    // ---------------- Phase 1: assignment + corrections (1 thread = 1 anchor)
    float my_corr = 0.f, my_reg = 0.f;   // my_corr in natural-log loss units
    int   my_pos  = 0;
    const int a = a0 + tid;
    if (tid < nA) {
        float4 ab = *(const float4*)(anchors + (size_t)a * 4);
        const float ax1 = ab.x, ay1 = ab.y, ax2 = ab.z, ay2 = ab.w;
        const float area_a = (ax2 - ax1) * (ay2 - ay1);
        float best = -2.f; int barg = 0;
        #pragma unroll
        for (int m = 0; m < M; ++m) {
            float iw = fminf(ax2, bx2[m]) - fmaxf(ax1, bx1[m]);
            float ih = fminf(ay2, by2[m]) - fmaxf(ay1, by1[m]);
            iw = fmaxf(iw, 0.f); ih = fmaxf(ih, 0.f);
            float inter = iw * ih;
            float ua  = fmaxf(area_a + barea[m] - inter, 1e-8f);
            float iou = inter / ua;
            if (blab[m] == -1.0f) iou = -1.0f;   // invalid annotation mask
            if (iou > best) { best = iou; barg = m; }
        }
        const bool pos = best >= 0.4f;   // IOU_THR + 0.1
        const bool neg = best < 0.3f;    // IOU_THR
        const float* row = cls + ((size_t)b * A + a) * C;
        if (pos) {
            my_pos = 1;
            const int cd = (int)blab[barg];
            float p = row[cd];
            p = fminf(fmaxf(p, 1e-4f), 0.9999f);
            const float omp = 1.f - p;
            // replace the streamed neg-term of the target column with the pos-term
            my_corr = 0.25f * omp * omp * (-__logf(p))
                    - 0.75f * p * p * (-__logf(omp));
            // regression smooth-L1
            const float aw = ax2 - ax1, ah = ay2 - ay1;
            const float acx = ax1 + 0.5f * aw, acy = ay1 + 0.5f * ah;
            float gw = bx2[barg] - bx1[barg], gh = by2[barg] - by1[barg];
            const float gcx = bx1[barg] + 0.5f * gw, gcy = by1[barg] + 0.5f * gh;
            gw = fmaxf(gw, 1.f); gh = fmaxf(gh, 1.f);
            const float t0 = ((gcx - acx) / aw) / 0.1f;
            const float t1 = ((gcy - acy) / ah) / 0.1f;
            const float t2 = __logf(gw / aw) / 0.2f;
            const float t3 = __logf(gh / ah) / 0.2f;
            float4 rp4 = *(const float4*)(regs + ((size_t)b * A + a) * 4);
            const float d0 = fabsf(t0 - rp4.x), d1 = fabsf(t1 - rp4.y);
            const float d2 = fabsf(t2 - rp4.z), d3 = fabsf(t3 - rp4.w);
            my_reg = (d0 <= 1.f ? 0.5f * d0 * d0 : d0 - 0.5f)
                   + (d1 <= 1.f ? 0.5f * d1 * d1 : d1 - 0.5f)
                   + (d2 <= 1.f ? 0.5f * d2 * d2 : d2 - 0.5f)
                   + (d3 <= 1.f ? 0.5f * d3 * d3 : d3 - 0.5f);
        } else if (!neg) {
            // ignore band: cancel this anchor's whole streamed row
            float c2 = 0.f;
            #pragma unroll 5
            for (int c4i = 0; c4i < C4; ++c4i) {
                float4 v = *(const float4*)(row + c4i * 4);
                c2 += v.x * v.x * __log2f(1.f - v.x)
                    + v.y * v.y * __log2f(1.f - v.y)
                    + v.z * v.z * __log2f(1.f - v.z)
                    + v.w * v.w * __log2f(1.f - v.w);
            }
            my_corr = NEG_SCALE * c2;    // c2 < 0: subtracts the streamed row
        }
    }
    // no __syncthreads(): phase 2 shares no state with phase 1

    // ---------------- Phase 2: pure stream, 4 batches x 5 float4 in flight
    float acc0 = 0.f, acc1 = 0.f;        // log2-space sums
    const float* base = cls + ((size_t)b * A + a0) * C;
    if (nA == APB) {
        #pragma unroll 1
        for (int batch = 0; batch < 4; ++batch) {
            const int i0 = tid + batch * (5 * APB);
            const float* p0 = base + (size_t)i0 * 4;
            float4 v0 = *(const float4*)(p0);
            float4 v1 = *(const float4*)(p0 + APB * 4);
            float4 v2 = *(const float4*)(p0 + 2 * APB * 4);
            float4 v3 = *(const float4*)(p0 + 3 * APB * 4);
            float4 v4 = *(const float4*)(p0 + 4 * APB * 4);
            acc0 = fmaf(v0.x * v0.x, __log2f(1.f - v0.x), acc0);
            acc1 = fmaf(v0.y * v0.y, __log2f(1.f - v0.y), acc1);
            acc0 = fmaf(v0.z * v0.z, __log2f(1.f - v0.z), acc0);
            acc1 = fmaf(v0.w * v0.w, __log2f(1.f - v0.w), acc1);
            acc0 = fmaf(v1.x * v1.x, __log2f(1.f - v1.x), acc0);
            acc1 = fmaf(v1.y * v1.y, __log2f(1.f - v1.y), acc1);
            acc0 = fmaf(v1.z * v1.z, __log2f(1.f - v1.z), acc0);
            acc1 = fmaf(v1.w * v1.w, __log2f(1.f - v1.w), acc1);
            acc0 = fmaf(v2.x * v2.x, __log2f(1.f - v2.x), acc0);
            acc1 = fmaf(v2.y * v2.y, __log2f(1.f - v2.y), acc1);
            acc0 = fmaf(v2.z * v2.z, __log2f(1.f - v2.z), acc0);
            acc1 = fmaf(v2.w * v2.w, __log2f(1.f - v2.w), acc1);
            acc0 = fmaf(v3.x * v3.x, __log2f(1.f - v3.x), acc0);
            acc1 = fmaf(v3.y * v3.y, __log2f(1.f - v3.y), acc1);
            acc0 = fmaf(v3.z * v3.z, __log2f(1.f - v3.z), acc0);
            acc1 = fmaf(v3.w * v3.w, __log2f(1.f - v3.w), acc1);
            acc0 = fmaf(v4.x * v4.x, __log2f(1.f - v4.x), acc0);
            acc1 = fmaf(v4.y * v4.y, __log2f(1.f - v4.y), acc1);
            acc0 = fmaf(v4.z * v4.z, __log2f(1.f - v4.z), acc0);
            acc1 = fmaf(v4.w * v4.w, __log2f(1.f - v4.w), acc1);
        }
    } else {
        const int n4 = nA * C4;
        for (int i = tid; i < n4; i += APB) {
            float4 v = *(const float4*)(base + (size_t)i * 4);
            acc0 = fmaf(v.x * v.x, __log2f(1.f - v.x), acc0);
            acc1 = fmaf(v.y * v.y, __log2f(1.f - v.y), acc1);
            acc0 = fmaf(v.z * v.z, __log2f(1.f - v.z), acc0);
            acc1 = fmaf(v.w * v.w, __log2f(1.f - v.w), acc1);
        }
    }
    // combine: stream contribution (-NEG_SCALE * S) + corrections
    float my_cls = fmaf(-NEG_SCALE, acc0 + acc1, my_corr);

    // ---------------- block reduction
    #pragma unroll
    for (int off = 32; off; off >>= 1) {
        my_cls += __shfl_down(my_cls, off);
        my_reg += __shfl_down(my_reg, off);
        my_pos += __shfl_down(my_pos, off);
    }
    const int wid = tid >> 6;
    if ((tid & 63) == 0) { rc[wid] = my_cls; rr[wid] = my_reg; rp[wid] = my_pos; }
    __syncthreads();
    if (tid == 0) {
        atomicAdd(&cls_acc[b], rc[0] + rc[1] + rc[2] + rc[3]);
        atomicAdd(&reg_acc[b], rr[0] + rr[1] + rr[2] + rr[3]);
        atomicAdd(&npos_acc[b], (unsigned)(rp[0] + rp[1] + rp[2] + rp[3]));
    }
}

__global__ void focal_finalize(const float* __restrict__ cls_acc,
                               const float* __restrict__ reg_acc,
                               const unsigned int* __restrict__ npos_acc,
                               float* __restrict__ out)
{
    if (threadIdx.x == 0) {
        float cm = 0.f, rm = 0.f; unsigned tot = 0u;
        #pragma unroll
        for (int b = 0; b < B; ++b) {
            const unsigned np = npos_acc[b];
            const float npf = (float)np;
            cm += cls_acc[b] / fmaxf(npf, 1.f);
            rm += (np > 0u) ? reg_acc[b] / fmaxf(npf * 4.f, 1.f) : 0.f;
            tot += np;
        }
        out[0] = cm / (float)B;
        out[1] = rm / (float)B;
        out[2] = (float)tot;
    }
}

extern "C" void kernel_launch(void* const* d_in, const int* in_sizes, int n_in,
                              void* d_out, int out_size, void* d_ws, size_t ws_size,
                              hipStream_t stream) {
    const float* cls     = (const float*)d_in[0];
    const float* regs    = (const float*)d_in[1];
    const float* anchors = (const float*)d_in[2];
    const float* ann     = (const float*)d_in[3];
    float* out = (float*)d_out;

    float* cls_acc = (float*)d_ws;
    float* reg_acc = cls_acc + B;
    unsigned int* npos_acc = (unsigned int*)(reg_acc + B);

    hipMemsetAsync(d_ws, 0, 3 * B * sizeof(float), stream);

    dim3 grid(NBLK, B);
    focal_main<<<grid, APB, 0, stream>>>(cls, regs, anchors, ann,
                                         cls_acc, reg_acc, npos_acc);
    focal_finalize<<<1, 64, 0, stream>>>(cls_acc, reg_acc, npos_acc, out);
}

// Round 5
// 109.644 us; speedup vs baseline: 2.0404x; 1.3488x over previous
//
#include <hip/hip_runtime.h>
#include <math.h>

constexpr int B = 8, A = 100000, C = 80, M = 32;
constexpr int APB = 256;                        // anchors per block
constexpr int NBLK = (A + APB - 1) / APB;       // 391 (last block: 160 anchors)
constexpr int C4 = C / 4;                       // 20 float4 per anchor row
constexpr float NEG_SCALE = 0.75f * 0.6931471805599453f; // 0.75*ln2

// d_ws layout: cls_acc[B], reg_acc[B], npos_acc[B]
__global__ __launch_bounds__(256, 4) void focal_main(
    const float* __restrict__ cls,       // [B,A,C]
    const float* __restrict__ regs,      // [B,A,4]
    const float* __restrict__ anchors,   // [1,A,4]
    const float* __restrict__ ann,       // [B,M,5]
    float* __restrict__ cls_acc,
    float* __restrict__ reg_acc,
    unsigned int* __restrict__ npos_acc)
{
    const int b   = blockIdx.y;
    const int a0  = blockIdx.x * APB;
    const int tid = threadIdx.x;
    const int nA  = min(APB, A - a0);

    __shared__ float bx1[M], by1[M], bx2[M], by2[M], blab[M], barea[M];
    __shared__ float rc[4], rr[4];
    __shared__ int   rp[4];

    if (tid < M) {
        const float* p = ann + ((size_t)b * M + tid) * 5;
        float x1 = p[0], y1 = p[1], x2 = p[2], y2 = p[3];
        bx1[tid] = x1; by1[tid] = y1; bx2[tid] = x2; by2[tid] = y2;
        blab[tid] = p[4];
        barea[tid] = (x2 - x1) * (y2 - y1);
    }
    __syncthreads();

    // ---------------- Phase 1: assignment + corrections (1 thread = 1 anchor)
    float my_corr = 0.f, my_reg = 0.f;   // my_corr in natural-log loss units
    int   my_pos  = 0;
    const int a = a0 + tid;
    if (tid < nA) {
        float4 ab = *(const float4*)(anchors + (size_t)a * 4);
        const float ax1 = ab.x, ay1 = ab.y, ax2 = ab.z, ay2 = ab.w;
        const float area_a = (ax2 - ax1) * (ay2 - ay1);
        float best = -2.f; int barg = 0;
        #pragma unroll
        for (int m = 0; m < M; ++m) {
            float iw = fminf(ax2, bx2[m]) - fmaxf(ax1, bx1[m]);
            float ih = fminf(ay2, by2[m]) - fmaxf(ay1, by1[m]);
            iw = fmaxf(iw, 0.f); ih = fmaxf(ih, 0.f);
            float inter = iw * ih;
            float ua  = fmaxf(area_a + barea[m] - inter, 1e-8f);
            float iou = inter / ua;
            if (blab[m] == -1.0f) iou = -1.0f;   // invalid annotation mask
            if (iou > best) { best = iou; barg = m; }
        }
        const bool pos = best >= 0.4f;   // IOU_THR + 0.1
        const bool neg = best < 0.3f;    // IOU_THR
        const float* row = cls + ((size_t)b * A + a) * C;
        if (pos) {
            my_pos = 1;
            const int cd = (int)blab[barg];
            float p = row[cd];
            p = fminf(fmaxf(p, 1e-4f), 0.9999f);
            const float omp = 1.f - p;
            // replace the streamed neg-term of the target column with the pos-term
            my_corr = 0.25f * omp * omp * (-__logf(p))
                    - 0.75f * p * p * (-__logf(omp));
            // regression smooth-L1
            const float aw = ax2 - ax1, ah = ay2 - ay1;
            const float acx = ax1 + 0.5f * aw, acy = ay1 + 0.5f * ah;
            float gw = bx2[barg] - bx1[barg], gh = by2[barg] - by1[barg];
            const float gcx = bx1[barg] + 0.5f * gw, gcy = by1[barg] + 0.5f * gh;
            gw = fmaxf(gw, 1.f); gh = fmaxf(gh, 1.f);
            const float t0 = ((gcx - acx) / aw) / 0.1f;
            const float t1 = ((gcy - acy) / ah) / 0.1f;
            const float t2 = __logf(gw / aw) / 0.2f;
            const float t3 = __logf(gh / ah) / 0.2f;
            float4 rp4 = *(const float4*)(regs + ((size_t)b * A + a) * 4);
            const float d0 = fabsf(t0 - rp4.x), d1 = fabsf(t1 - rp4.y);
            const float d2 = fabsf(t2 - rp4.z), d3 = fabsf(t3 - rp4.w);
            my_reg = (d0 <= 1.f ? 0.5f * d0 * d0 : d0 - 0.5f)
                   + (d1 <= 1.f ? 0.5f * d1 * d1 : d1 - 0.5f)
                   + (d2 <= 1.f ? 0.5f * d2 * d2 : d2 - 0.5f)
                   + (d3 <= 1.f ? 0.5f * d3 * d3 : d3 - 0.5f);
        } else if (!neg) {
            // ignore band: cancel this anchor's whole streamed row
            float c2 = 0.f;
            #pragma unroll 5
            for (int c4i = 0; c4i < C4; ++c4i) {
                float4 v = *(const float4*)(row + c4i * 4);
                c2 += v.x * v.x * __log2f(1.f - v.x)
                    + v.y * v.y * __log2f(1.f - v.y)
                    + v.z * v.z * __log2f(1.f - v.z)
                    + v.w * v.w * __log2f(1.f - v.w);
            }
            my_corr = NEG_SCALE * c2;    // c2 < 0: subtracts the streamed row
        }
    }
    // no __syncthreads(): phase 2 shares no state with phase 1

    // ---------------- Phase 2: pure stream, 4 batches x 5 float4 in flight
    float acc0 = 0.f, acc1 = 0.f;        // log2-space sums
    const float* base = cls + ((size_t)b * A + a0) * C;
    if (nA == APB) {
        #pragma unroll 1
        for (int batch = 0; batch < 4; ++batch) {
            const int i0 = tid + batch * (5 * APB);
            const float* p0 = base + (size_t)i0 * 4;
            float4 v0 = *(const float4*)(p0);
            float4 v1 = *(const float4*)(p0 + APB * 4);
            float4 v2 = *(const float4*)(p0 + 2 * APB * 4);
            float4 v3 = *(const float4*)(p0 + 3 * APB * 4);
            float4 v4 = *(const float4*)(p0 + 4 * APB * 4);
            acc0 = fmaf(v0.x * v0.x, __log2f(1.f - v0.x), acc0);
            acc1 = fmaf(v0.y * v0.y, __log2f(1.f - v0.y), acc1);
            acc0 = fmaf(v0.z * v0.z, __log2f(1.f - v0.z), acc0);
            acc1 = fmaf(v0.w * v0.w, __log2f(1.f - v0.w), acc1);
            acc0 = fmaf(v1.x * v1.x, __log2f(1.f - v1.x), acc0);
            acc1 = fmaf(v1.y * v1.y, __log2f(1.f - v1.y), acc1);
            acc0 = fmaf(v1.z * v1.z, __log2f(1.f - v1.z), acc0);
            acc1 = fmaf(v1.w * v1.w, __log2f(1.f - v1.w), acc1);
            acc0 = fmaf(v2.x * v2.x, __log2f(1.f - v2.x), acc0);
            acc1 = fmaf(v2.y * v2.y, __log2f(1.f - v2.y), acc1);
            acc0 = fmaf(v2.z * v2.z, __log2f(1.f - v2.z), acc0);
            acc1 = fmaf(v2.w * v2.w, __log2f(1.f - v2.w), acc1);
            acc0 = fmaf(v3.x * v3.x, __log2f(1.f - v3.x), acc0);
            acc1 = fmaf(v3.y * v3.y, __log2f(1.f - v3.y), acc1);
            acc0 = fmaf(v3.z * v3.z, __log2f(1.f - v3.z), acc0);
            acc1 = fmaf(v3.w * v3.w, __log2f(1.f - v3.w), acc1);
            acc0 = fmaf(v4.x * v4.x, __log2f(1.f - v4.x), acc0);
            acc1 = fmaf(v4.y * v4.y, __log2f(1.f - v4.y), acc1);
            acc0 = fmaf(v4.z * v4.z, __log2f(1.f - v4.z), acc0);
            acc1 = fmaf(v4.w * v4.w, __log2f(1.f - v4.w), acc1);
        }
    } else {
        const int n4 = nA * C4;
        for (int i = tid; i < n4; i += APB) {
            float4 v = *(const float4*)(base + (size_t)i * 4);
            acc0 = fmaf(v.x * v.x, __log2f(1.f - v.x), acc0);
            acc1 = fmaf(v.y * v.y, __log2f(1.f - v.y), acc1);
            acc0 = fmaf(v.z * v.z, __log2f(1.f - v.z), acc0);
            acc1 = fmaf(v.w * v.w, __log2f(1.f - v.w), acc1);
        }
    }
    // combine: stream contribution (-NEG_SCALE * S) + corrections
    float my_cls = fmaf(-NEG_SCALE, acc0 + acc1, my_corr);

    // ---------------- block reduction
    #pragma unroll
    for (int off = 32; off; off >>= 1) {
        my_cls += __shfl_down(my_cls, off);
        my_reg += __shfl_down(my_reg, off);
        my_pos += __shfl_down(my_pos, off);
    }
    const int wid = tid >> 6;
    if ((tid & 63) == 0) { rc[wid] = my_cls; rr[wid] = my_reg; rp[wid] = my_pos; }
    __syncthreads();
    if (tid == 0) {
        atomicAdd(&cls_acc[b], rc[0] + rc[1] + rc[2] + rc[3]);
        atomicAdd(&reg_acc[b], rr[0] + rr[1] + rr[2] + rr[3]);
        atomicAdd(&npos_acc[b], (unsigned)(rp[0] + rp[1] + rp[2] + rp[3]));
    }
}

__global__ void focal_finalize(const float* __restrict__ cls_acc,
                               const float* __restrict__ reg_acc,
                               const unsigned int* __restrict__ npos_acc,
                               float* __restrict__ out)
{
    if (threadIdx.x == 0) {
        float cm = 0.f, rm = 0.f; unsigned tot = 0u;
        #pragma unroll
        for (int b = 0; b < B; ++b) {
            const unsigned np = npos_acc[b];
            const float npf = (float)np;
            cm += cls_acc[b] / fmaxf(npf, 1.f);
            rm += (np > 0u) ? reg_acc[b] / fmaxf(npf * 4.f, 1.f) : 0.f;
            tot += np;
        }
        out[0] = cm / (float)B;
        out[1] = rm / (float)B;
        out[2] = (float)tot;
    }
}

extern "C" void kernel_launch(void* const* d_in, const int* in_sizes, int n_in,
                              void* d_out, int out_size, void* d_ws, size_t ws_size,
                              hipStream_t stream) {
    const float* cls     = (const float*)d_in[0];
    const float* regs    = (const float*)d_in[1];
    const float* anchors = (const float*)d_in[2];
    const float* ann     = (const float*)d_in[3];
    float* out = (float*)d_out;

    float* cls_acc = (float*)d_ws;
    float* reg_acc = cls_acc + B;
    unsigned int* npos_acc = (unsigned int*)(reg_acc + B);

    hipMemsetAsync(d_ws, 0, 3 * B * sizeof(float), stream);

    dim3 grid(NBLK, B);
    focal_main<<<grid, APB, 0, stream>>>(cls, regs, anchors, ann,
                                         cls_acc, reg_acc, npos_acc);
    focal_finalize<<<1, 64, 0, stream>>>(cls_acc, reg_acc, npos_acc, out);
}

// Round 6
// 109.241 us; speedup vs baseline: 2.0479x; 1.0037x over previous
//
#include <hip/hip_runtime.h>
#include <math.h>

constexpr int B = 8, A = 100000, C = 80, M = 32;
constexpr int APB = 256;                        // anchors per block
constexpr int NBLK = (A + APB - 1) / APB;       // 391 (last block: 160 anchors)
constexpr int C4 = C / 4;                       // 20 float4 per anchor row
constexpr float NEG_SCALE = 0.75f * 0.6931471805599453f; // 0.75*ln2

// d_ws layout: cls_acc[B], reg_acc[B], npos_acc[B]
__global__ __launch_bounds__(256, 4) void focal_main(
    const float* __restrict__ cls,       // [B,A,C]
    const float* __restrict__ regs,      // [B,A,4]
    const float* __restrict__ anchors,   // [1,A,4]
    const float* __restrict__ ann,       // [B,M,5]
    float* __restrict__ cls_acc,
    float* __restrict__ reg_acc,
    unsigned int* __restrict__ npos_acc)
{
    const int b   = blockIdx.y;
    const int a0  = blockIdx.x * APB;
    const int tid = threadIdx.x;
    const int nA  = min(APB, A - a0);

    __shared__ float bx1[M], by1[M], bx2[M], by2[M], blab[M], barea[M];
    __shared__ float rc[4], rr[4];
    __shared__ int   rp[4];

    if (tid < M) {
        const float* p = ann + ((size_t)b * M + tid) * 5;
        float x1 = p[0], y1 = p[1], x2 = p[2], y2 = p[3];
        bx1[tid] = x1; by1[tid] = y1; bx2[tid] = x2; by2[tid] = y2;
        blab[tid] = p[4];
        barea[tid] = (x2 - x1) * (y2 - y1);
    }
    __syncthreads();

    // ---------------- Phase 1: assignment + corrections (1 thread = 1 anchor)
    float my_corr = 0.f, my_reg = 0.f;   // my_corr in natural-log loss units
    int   my_pos  = 0;
    const int a = a0 + tid;
    if (tid < nA) {
        float4 ab = *(const float4*)(anchors + (size_t)a * 4);
        const float ax1 = ab.x, ay1 = ab.y, ax2 = ab.z, ay2 = ab.w;
        const float area_a = (ax2 - ax1) * (ay2 - ay1);
        float best = -2.f; int barg = 0;
        #pragma unroll
        for (int m = 0; m < M; ++m) {
            float iw = fminf(ax2, bx2[m]) - fmaxf(ax1, bx1[m]);
            float ih = fminf(ay2, by2[m]) - fmaxf(ay1, by1[m]);
            iw = fmaxf(iw, 0.f); ih = fmaxf(ih, 0.f);
            float inter = iw * ih;
            float ua  = fmaxf(area_a + barea[m] - inter, 1e-8f);
            float iou = inter / ua;
            if (blab[m] == -1.0f) iou = -1.0f;   // invalid annotation mask
            if (iou > best) { best = iou; barg = m; }
        }
        const bool pos = best >= 0.4f;   // IOU_THR + 0.1
        const bool neg = best < 0.3f;    // IOU_THR
        const float* row = cls + ((size_t)b * A + a) * C;
        if (pos) {
            my_pos = 1;
            const int cd = (int)blab[barg];
            float p = row[cd];
            p = fminf(fmaxf(p, 1e-4f), 0.9999f);
            const float omp = 1.f - p;
            // replace the streamed neg-term of the target column with the pos-term
            my_corr = 0.25f * omp * omp * (-__logf(p))
                    - 0.75f * p * p * (-__logf(omp));
            // regression smooth-L1
            const float aw = ax2 - ax1, ah = ay2 - ay1;
            const float acx = ax1 + 0.5f * aw, acy = ay1 + 0.5f * ah;
            float gw = bx2[barg] - bx1[barg], gh = by2[barg] - by1[barg];
            const float gcx = bx1[barg] + 0.5f * gw, gcy = by1[barg] + 0.5f * gh;
            gw = fmaxf(gw, 1.f); gh = fmaxf(gh, 1.f);
            const float t0 = ((gcx - acx) / aw) / 0.1f;
            const float t1 = ((gcy - acy) / ah) / 0.1f;
            const float t2 = __logf(gw / aw) / 0.2f;
            const float t3 = __logf(gh / ah) / 0.2f;
            float4 rp4 = *(const float4*)(regs + ((size_t)b * A + a) * 4);
            const float d0 = fabsf(t0 - rp4.x), d1 = fabsf(t1 - rp4.y);
            const float d2 = fabsf(t2 - rp4.z), d3 = fabsf(t3 - rp4.w);
            my_reg = (d0 <= 1.f ? 0.5f * d0 * d0 : d0 - 0.5f)
                   + (d1 <= 1.f ? 0.5f * d1 * d1 : d1 - 0.5f)
                   + (d2 <= 1.f ? 0.5f * d2 * d2 : d2 - 0.5f)
                   + (d3 <= 1.f ? 0.5f * d3 * d3 : d3 - 0.5f);
        } else if (!neg) {
            // ignore band: cancel this anchor's whole streamed row
            float c2 = 0.f;
            #pragma unroll 5
            for (int c4i = 0; c4i < C4; ++c4i) {
                float4 v = *(const float4*)(row + c4i * 4);
                c2 += v.x * v.x * __log2f(1.f - v.x)
                    + v.y * v.y * __log2f(1.f - v.y)
                    + v.z * v.z * __log2f(1.f - v.z)
                    + v.w * v.w * __log2f(1.f - v.w);
            }
            my_corr = NEG_SCALE * c2;    // c2 < 0: subtracts the streamed row
        }
    }
    // no __syncthreads(): phase 2 shares no state with phase 1

    // ---------------- Phase 2: pure stream, double-buffered 4-deep pipeline,
    // 5 groups x 4 float4 per thread (20 float4 = 5120 f4/block).
    float acc0 = 0.f, acc1 = 0.f, acc2 = 0.f, acc3 = 0.f;  // log2-space sums
    const float* base = cls + ((size_t)b * A + a0) * C;
    if (nA == APB) {
        const float4* p = (const float4*)base + tid;
        float4 c0 = p[0 * APB];
        float4 c1 = p[1 * APB];
        float4 c2 = p[2 * APB];
        float4 c3 = p[3 * APB];
        #pragma unroll
        for (int g = 0; g < 5; ++g) {
            float4 n0, n1, n2, n3;
            if (g < 4) {
                const float4* q = p + (g + 1) * 4 * APB;
                n0 = q[0 * APB];
                n1 = q[1 * APB];
                n2 = q[2 * APB];
                n3 = q[3 * APB];
            }
            acc0 = fmaf(c0.x * c0.x, __log2f(1.f - c0.x), acc0);
            acc1 = fmaf(c0.y * c0.y, __log2f(1.f - c0.y), acc1);
            acc2 = fmaf(c0.z * c0.z, __log2f(1.f - c0.z), acc2);
            acc3 = fmaf(c0.w * c0.w, __log2f(1.f - c0.w), acc3);
            acc0 = fmaf(c1.x * c1.x, __log2f(1.f - c1.x), acc0);
            acc1 = fmaf(c1.y * c1.y, __log2f(1.f - c1.y), acc1);
            acc2 = fmaf(c1.z * c1.z, __log2f(1.f - c1.z), acc2);
            acc3 = fmaf(c1.w * c1.w, __log2f(1.f - c1.w), acc3);
            acc0 = fmaf(c2.x * c2.x, __log2f(1.f - c2.x), acc0);
            acc1 = fmaf(c2.y * c2.y, __log2f(1.f - c2.y), acc1);
            acc2 = fmaf(c2.z * c2.z, __log2f(1.f - c2.z), acc2);
            acc3 = fmaf(c2.w * c2.w, __log2f(1.f - c2.w), acc3);
            acc0 = fmaf(c3.x * c3.x, __log2f(1.f - c3.x), acc0);
            acc1 = fmaf(c3.y * c3.y, __log2f(1.f - c3.y), acc1);
            acc2 = fmaf(c3.z * c3.z, __log2f(1.f - c3.z), acc2);
            acc3 = fmaf(c3.w * c3.w, __log2f(1.f - c3.w), acc3);
            if (g < 4) { c0 = n0; c1 = n1; c2 = n2; c3 = n3; }
        }
    } else {
        const int n4 = nA * C4;
        for (int i = tid; i < n4; i += APB) {
            float4 v = *(const float4*)(base + (size_t)i * 4);
            acc0 = fmaf(v.x * v.x, __log2f(1.f - v.x), acc0);
            acc1 = fmaf(v.y * v.y, __log2f(1.f - v.y), acc1);
            acc2 = fmaf(v.z * v.z, __log2f(1.f - v.z), acc2);
            acc3 = fmaf(v.w * v.w, __log2f(1.f - v.w), acc3);
        }
    }
    // combine: stream contribution (-NEG_SCALE * S) + corrections
    float my_cls = fmaf(-NEG_SCALE, (acc0 + acc1) + (acc2 + acc3), my_corr);

    // ---------------- block reduction
    #pragma unroll
    for (int off = 32; off; off >>= 1) {
        my_cls += __shfl_down(my_cls, off);
        my_reg += __shfl_down(my_reg, off);
        my_pos += __shfl_down(my_pos, off);
    }
    const int wid = tid >> 6;
    if ((tid & 63) == 0) { rc[wid] = my_cls; rr[wid] = my_reg; rp[wid] = my_pos; }
    __syncthreads();
    if (tid == 0) {
        atomicAdd(&cls_acc[b], rc[0] + rc[1] + rc[2] + rc[3]);
        atomicAdd(&reg_acc[b], rr[0] + rr[1] + rr[2] + rr[3]);
        atomicAdd(&npos_acc[b], (unsigned)(rp[0] + rp[1] + rp[2] + rp[3]));
    }
}

__global__ void focal_finalize(const float* __restrict__ cls_acc,
                               const float* __restrict__ reg_acc,
                               const unsigned int* __restrict__ npos_acc,
                               float* __restrict__ out)
{
    if (threadIdx.x == 0) {
        float cm = 0.f, rm = 0.f; unsigned tot = 0u;
        #pragma unroll
        for (int b = 0; b < B; ++b) {
            const unsigned np = npos_acc[b];
            const float npf = (float)np;
            cm += cls_acc[b] / fmaxf(npf, 1.f);
            rm += (np > 0u) ? reg_acc[b] / fmaxf(npf * 4.f, 1.f) : 0.f;
            tot += np;
        }
        out[0] = cm / (float)B;
        out[1] = rm / (float)B;
        out[2] = (float)tot;
    }
}

extern "C" void kernel_launch(void* const* d_in, const int* in_sizes, int n_in,
                              void* d_out, int out_size, void* d_ws, size_t ws_size,
                              hipStream_t stream) {
    const float* cls     = (const float*)d_in[0];
    const float* regs    = (const float*)d_in[1];
    const float* anchors = (const float*)d_in[2];
    const float* ann     = (const float*)d_in[3];
    float* out = (float*)d_out;

    float* cls_acc = (float*)d_ws;
    float* reg_acc = cls_acc + B;
    unsigned int* npos_acc = (unsigned int*)(reg_acc + B);

    hipMemsetAsync(d_ws, 0, 3 * B * sizeof(float), stream);

    dim3 grid(NBLK, B);
    focal_main<<<grid, APB, 0, stream>>>(cls, regs, anchors, ann,
                                         cls_acc, reg_acc, npos_acc);
    focal_finalize<<<1, 64, 0, stream>>>(cls_acc, reg_acc, npos_acc, out);
}